// Round 8
// baseline (286.718 us; speedup 1.0000x reference)
//
#include <hip/hip_runtime.h>
#include <math.h>

#define NCLS 31
#define B 4096
#define D 512
#define N 8192
#define BT 128
#define NT (N / BT)               // 64 tiles per dim
#define NBLK (NT * (NT + 1) / 2)  // 2080 upper-tri tiles
#define BK32 32                   // bf16 K-chunk per iteration (triple-buffered)
#define NITER 16                  // K=512: pure-bf16 X dot (error ~5e-7 << 1.2e-4 thr)
#define NCHUNK 256                // pre chunks (32 rows each), work-stolen
#define MAGIC 0x7E57A5A5u

// ws float-index layout (memset zeroes first 24576 B = 6144 floats)
#define WS_SUMSQB 0      // 8 bucketed sumsq accumulators
#define WS_NBT    9
#define WS_SL     10
#define WS_CNT    11     // int done-counter (tiles)
#define WS_CNT2   12     // int done-counter (pre chunks)
#define WS_PREC   13     // int steal counter (pre chunks)
#define WS_FLAG   192    // stats-ready flag, ISOLATED cache line (floats 192..223 reserved)
#define WS_HIST   16     // 31 ints
#define WS_PRES   47     // unsigned mask
#define WS_CSUM   48     // 31 floats
#define WS_SVAL   80     // 32
#define WS_TVAL   112    // 32
#define WS_ACCB   256    // 64 buckets, stride 16 floats (one line each)
#define WS_COLP   1280   // 8*512 bucketed column-sum partials (ends 5376)
#define WS_SQ     5376   // 8192 row squared norms (fully overwritten pre-FLAG)
#define WS_XC_BYTES 65536  // Xc: bf16 [8192][512] row-major, 8 MB

typedef __attribute__((ext_vector_type(8))) short bf16x8;
typedef __attribute__((ext_vector_type(4))) float f32x4;
typedef __attribute__((ext_vector_type(8))) unsigned short u16x8;

__device__ __forceinline__ unsigned short f2bf(float x) {
  unsigned u = __float_as_uint(x);
  u += 0x7fffu + ((u >> 16) & 1u);  // RNE (inputs finite)
  return (unsigned short)(u >> 16);
}
__device__ __forceinline__ float bf2f(unsigned short b) {
  return __uint_as_float(((unsigned)b) << 16);
}

__device__ __forceinline__ void async_lds16(const unsigned short* g, const short* l) {
  __builtin_amdgcn_global_load_lds(
      (const __attribute__((address_space(1))) unsigned int*)g,
      (__attribute__((address_space(3))) unsigned int*)l, 16, 0, 0);
}

// BK=32 tile: rows of 64 B = 4 granules of 16 B; XOR swizzle on (r>>1)&3
__device__ __forceinline__ bf16x8 frag32(const short* buf, int r, int g) {
  int sg = g ^ ((r >> 1) & 3);
  return *(const bf16x8*)(buf + (r * 4 + sg) * 8);
}

// R8: SINGLE kernel. The ~80 µs k_pre+boundary cost was invariant across five
// k_pre implementations (R0-R7) and absent in the single-kernel R5 (residual
// 24 µs) -> delete the boundary. Every block work-steals pre chunks (claimed
// only by RESIDENT blocks -> claimants progress -> counter drains -> finalizer
// publishes FLAG; spinners wait only on claimants: deadlock-free with NO
// dispatch-order assumption, G16-clean). Tile phase = R4 body verbatim,
// straight-line (R5's persistent-loop tile slowdown avoided).
__launch_bounds__(256, 3)
__global__ void k_all(const float* __restrict__ src, const float* __restrict__ tgt,
                      const int* __restrict__ label, const float* __restrict__ logits,
                      const int* __restrict__ iter_p, float* __restrict__ wsf,
                      unsigned short* __restrict__ Xc, float* __restrict__ out) {
  __shared__ __align__(16) short tA[3][BT * BK32];   // 3 x 8 KB
  __shared__ __align__(16) short tB[3][BT * BK32];   // 3 x 8 KB
  __shared__ float sqi[BT], sqj[BT];
  __shared__ float red[4];
  __shared__ int lcnt[32];
  __shared__ float lcsum[32];
  __shared__ unsigned lpres;
  __shared__ int schunk;
  __shared__ int finblk;

  const int tid = threadIdx.x;
  const int w = tid >> 6, lane = tid & 63;

  // ================= phase A: work-steal pre chunks =================
  {
    float (*colbuf)[512] = (float (*)[512])tA;   // 8 KB carve of tA
    for (;;) {
      if (tid == 0) schunk = atomicAdd((int*)&wsf[WS_PREC], 1);
      __syncthreads();
      const int c = schunk;
      if (c >= NCHUNK) break;
      if (tid < 32) { lcnt[tid] = 0; lcsum[tid] = 0.f; }
      if (tid == 0) lpres = 0u;

      // 32 rows: convert -> Xc, row sq -> WS_SQ, register colsums
      float4 ca = {0.f, 0.f, 0.f, 0.f}, cb = {0.f, 0.f, 0.f, 0.f};
      float wssq = 0.f;
      #pragma unroll
      for (int r = 0; r < 8; ++r) {
        const int row = c * 32 + r * 4 + w;
        const float* p = (row < B) ? src + (size_t)row * D
                                   : tgt + (size_t)(row - B) * D;
        float4 a  = ((const float4*)p)[lane];        // cols lane*4 .. +4
        float4 bb = ((const float4*)p)[lane + 64];   // cols 256+lane*4 .. +4
        ushort4 ha, hb;
        ha.x = f2bf(a.x); ha.y = f2bf(a.y); ha.z = f2bf(a.z); ha.w = f2bf(a.w);
        hb.x = f2bf(bb.x); hb.y = f2bf(bb.y); hb.z = f2bf(bb.z); hb.w = f2bf(bb.w);
        size_t rb8 = (size_t)row * 512;
        *(ushort4*)(Xc + rb8 + lane * 4)       = ha;
        *(ushort4*)(Xc + rb8 + 256 + lane * 4) = hb;
        float s = a.x*a.x + a.y*a.y + a.z*a.z + a.w*a.w
                + bb.x*bb.x + bb.y*bb.y + bb.z*bb.z + bb.w*bb.w;
        ca.x += a.x;  ca.y += a.y;  ca.z += a.z;  ca.w += a.w;
        cb.x += bb.x; cb.y += bb.y; cb.z += bb.z; cb.w += bb.w;
        #pragma unroll
        for (int off = 32; off; off >>= 1) s += __shfl_down(s, off);
        if (lane == 0) { wsf[WS_SQ + row] = s; wssq += s; }
      }

      // class stats for rows [c*32, c*32+32) — wave 0 only (same-wave ordering)
      const int r0 = c * 32;
      if (r0 < B) {
        if (tid < 32) atomicAdd(&lcnt[label[r0 + tid]], 1);
      } else if (tid < 32) {
        const float* lp = logits + (size_t)(r0 - B + tid) * NCLS;
        float mx = -1e30f; int am = 0;
        #pragma unroll
        for (int cc = 0; cc < NCLS; cc++) {
          float v = lp[cc];
          atomicAdd(&lcsum[cc], v);
          if (v > mx) { mx = v; am = cc; }  // strict >: first max = argmax
        }
        atomicOr(&lpres, 1u << am);
      }

      // cross-wave column reduce
      *(float4*)&colbuf[w][lane * 4]       = ca;
      *(float4*)&colbuf[w][256 + lane * 4] = cb;
      if (lane == 0) red[w] = wssq;
      __syncthreads();
      {
        float c0 = colbuf[0][tid] + colbuf[1][tid] + colbuf[2][tid] + colbuf[3][tid];
        float c1 = colbuf[0][tid+256] + colbuf[1][tid+256]
                 + colbuf[2][tid+256] + colbuf[3][tid+256];
        const int bkt = (c & 7) * 512;
        atomicAdd(&wsf[WS_COLP + bkt + tid], c0);          // memset-zeroed buckets
        atomicAdd(&wsf[WS_COLP + bkt + 256 + tid], c1);
        if (tid == 0)
          atomicAdd(&wsf[WS_SUMSQB + (c & 7)], red[0] + red[1] + red[2] + red[3]);
        if (r0 < B) {
          if (tid < NCLS && lcnt[tid]) atomicAdd((int*)&wsf[WS_HIST] + tid, lcnt[tid]);
        } else {
          if (tid < NCLS) atomicAdd(&wsf[WS_CSUM + tid], lcsum[tid]);
          if (tid == 0) atomicOr((unsigned*)&wsf[WS_PRES], lpres);
        }
      }
      __syncthreads();   // all atomics drained (vmcnt=0 at barrier) before release
      if (tid == 0)
        finblk = (__hip_atomic_fetch_add((int*)&wsf[WS_CNT2], 1,
                  __ATOMIC_ACQ_REL, __HIP_MEMORY_SCOPE_AGENT) == NCHUNK - 1);
      __syncthreads();
      if (finblk) {
        // last chunk done: finalize stats (all partials visible via ACQ_REL chain)
        float cs0 = 0.f, cs1 = 0.f;
        #pragma unroll
        for (int bk = 0; bk < 8; bk++) {
          cs0 += wsf[WS_COLP + bk * 512 + tid];
          cs1 += wsf[WS_COLP + bk * 512 + 256 + tid];
        }
        float v = cs0 * cs0 + cs1 * cs1;
        #pragma unroll
        for (int off = 32; off; off >>= 1) v += __shfl_down(v, off);
        if (lane == 0) red[w] = v;
        __syncthreads();
        if (tid < 32) {
          unsigned presT = *(unsigned*)&wsf[WS_PRES];
          int cnt = (tid < NCLS) ? ((int*)&wsf[WS_HIST])[tid] : 0;
          float csum = (tid < NCLS) ? wsf[WS_CSUM + tid] : 0.f;
          bool m = (cnt > 0) && ((presT >> tid) & 1u);
          if (csum == 0.f) csum = 100.f;
          wsf[WS_SVAL + tid] = m ? 1.f / (float)cnt : 0.f;
          wsf[WS_TVAL + tid] = m ? -1.f / csum : 0.f;
          unsigned long long bal = __ballot(m);
          if (tid == 0) {
            int cm = __popcll(bal);
            float scale = (cm > 0) ? 1.f / (float)cm : 0.f;
            float pp = (float)iter_p[0] / 1000.f;
            float lamb = 2.f / (1.f + __expf(-pp)) - 1.f;
            wsf[WS_SL] = scale * lamb;
            double colnorm2 = (double)red[0] + red[1] + red[2] + red[3];
            double sumsq = 0.0;
            for (int bk = 0; bk < 8; bk++) sumsq += (double)wsf[WS_SUMSQB + bk];
            double sumL2 = 2.0 * (double)N * sumsq - 2.0 * colnorm2;
            wsf[WS_NBT] = (float)(-((double)N * (double)N - (double)N) / (4.0 * sumL2));
          }
        }
        __syncthreads();   // stats stores (tid<32) complete before release
        if (tid == 0)
          __hip_atomic_store((unsigned*)&wsf[WS_FLAG], MAGIC,
                             __ATOMIC_RELEASE, __HIP_MEMORY_SCOPE_AGENT);
      }
      __syncthreads();   // colbuf free for next chunk
    }

    // wait for stats (bounded: chunks held only by resident, progressing blocks)
    if (tid == 0) {
      while (__hip_atomic_load((unsigned*)&wsf[WS_FLAG], __ATOMIC_RELAXED,
                               __HIP_MEMORY_SCOPE_AGENT) != MAGIC)
        __builtin_amdgcn_s_sleep(16);
    }
    __syncthreads();
    __builtin_amdgcn_fence(__ATOMIC_ACQUIRE, "agent");  // invalidate stale lines
  }

  // ================= phase B: one 128x128 tile (R4 body verbatim) =================
  int bid = blockIdx.x;
  int bi = (int)(64.5f - sqrtf(64.5f * 64.5f - 2.0f * (float)bid));
  while (bi > 0 && bid < (bi * (129 - bi)) / 2) --bi;
  while (bid >= ((bi + 1) * (128 - bi)) / 2) ++bi;
  int bj = bi + (bid - (bi * (129 - bi)) / 2);
  const int i0 = bi * BT, j0 = bj * BT;
  const float mult = (bi == bj) ? 1.f : 2.f;

  const int woff_m = (w >> 1) * 64, woff_n = (w & 1) * 64;
  const int fr = lane & 15, fg = lane >> 4;       // fragment row / k-group
  const int s_r  = lane >> 2;                     // r_local 0..15
  const int s_g  = (lane & 3) ^ ((s_r >> 1) & 3); // logical granule (inverts swizzle)

  #define ISSUE(it, bf) do {                                                   \
    const int off = (it) * 32;                                                 \
    _Pragma("unroll")                                                          \
    for (int q = 0; q < 2; ++q) {                                              \
      const int inst = w * 2 + q;              /* 0..7, 16 rows each */        \
      const int rl = inst * 16 + s_r;                                          \
      async_lds16(Xc + (size_t)(i0 + rl) * 512 + off + s_g * 8,                \
                  &tA[bf][inst * 512]);                                        \
      async_lds16(Xc + (size_t)(j0 + rl) * 512 + off + s_g * 8,                \
                  &tB[bf][inst * 512]);                                        \
    }                                                                          \
  } while (0)

  ISSUE(0, 0);
  ISSUE(1, 1);

  if (tid < 128) sqi[tid] = wsf[WS_SQ + i0 + tid];
  else           sqj[tid - 128] = wsf[WS_SQ + j0 + (tid - 128)];
  const float nbt = wsf[WS_NBT];

  f32x4 acc[4][4];
  #pragma unroll
  for (int mt = 0; mt < 4; mt++)
    #pragma unroll
    for (int nt = 0; nt < 4; nt++) acc[mt][nt] = (f32x4){0.f, 0.f, 0.f, 0.f};

  __syncthreads();  // full drain: buf0/buf1 staged, sq/nbt loads retired (vmcnt=0)

  #pragma unroll
  for (int it = 0; it < NITER; ++it) {
    if (it >= 1) {
      if (it >= 2 && it < NITER - 1)
        asm volatile("s_waitcnt vmcnt(4)" ::: "memory");
      if (it == NITER - 1)
        asm volatile("s_waitcnt vmcnt(0)" ::: "memory");
      __builtin_amdgcn_s_barrier();
      __builtin_amdgcn_sched_barrier(0);
    }
    const int cur = it % 3;
    bf16x8 af[4], bfr[4];
    #pragma unroll
    for (int mt = 0; mt < 4; mt++)
      af[mt] = frag32(tA[cur], woff_m + mt * 16 + fr, fg);
    #pragma unroll
    for (int nt = 0; nt < 4; nt++)
      bfr[nt] = frag32(tB[cur], woff_n + nt * 16 + fr, fg);
    if (it + 2 < NITER) ISSUE(it + 2, (it + 2) % 3);
    #pragma unroll
    for (int mt = 0; mt < 4; mt++)
      #pragma unroll
      for (int nt = 0; nt < 4; nt++)
        acc[mt][nt] = __builtin_amdgcn_mfma_f32_16x16x32_bf16(
            af[mt], bfr[nt], acc[mt][nt], 0, 0, 0);
  }
  #undef ISSUE

  // acc -> multi-band Gaussian kernel: t + t^2 + t^4 + t^8 + t^16
  float sj4[4], si16[4][4];
  #pragma unroll
  for (int nt = 0; nt < 4; nt++) sj4[nt] = sqj[woff_n + nt * 16 + fr];
  #pragma unroll
  for (int mt = 0; mt < 4; mt++)
    #pragma unroll
    for (int t = 0; t < 4; t++) si16[mt][t] = sqi[woff_m + mt * 16 + fg * 4 + t];
  #pragma unroll
  for (int mt = 0; mt < 4; mt++)
    #pragma unroll
    for (int nt = 0; nt < 4; nt++)
      #pragma unroll
      for (int t = 0; t < 4; t++) {
        float d2 = fmaxf(si16[mt][t] + sj4[nt] - 2.f * acc[mt][nt][t], 0.f);
        float e1 = __expf(d2 * nbt);
        float e2 = e1 * e1, e4 = e2 * e2, e8 = e4 * e4, e16 = e8 * e8;
        acc[mt][nt][t] = ((e16 + e8) + (e4 + e2)) + e1;
      }

  // build Q tiles: Qi-hi->tA[0], Qi-lo->tA[1], Qj-hi->tB[0], Qj-lo->tB[1]
  __syncthreads();
  {
    const int t = tid & 127;
    short* qh = (tid < 128) ? tA[0] : tB[0];
    short* ql = (tid < 128) ? tA[1] : tB[1];
    const int gq = ((tid < 128) ? i0 : j0) + t;
    const int lab = (gq < B) ? label[gq] : -1;
    const float sv = (gq < B) ? wsf[WS_SVAL + lab] : 0.f;
    const float* lp = (gq < B) ? (const float*)0 : logits + (size_t)(gq - B) * NCLS;
    #pragma unroll
    for (int g = 0; g < 4; ++g) {
      u16x8 ph = (u16x8){0,0,0,0,0,0,0,0}, pl = (u16x8){0,0,0,0,0,0,0,0};
      const int cbase = g * 8;
      if (gq < B) {
        if (lab >= cbase && lab < cbase + 8) {
          unsigned short h = f2bf(sv);
          ph[lab - cbase] = h;
          pl[lab - cbase] = f2bf(sv - bf2f(h));
        }
      } else {
        #pragma unroll
        for (int jc = 0; jc < 8; ++jc) {
          int cc = cbase + jc;
          if (cc < NCLS) {
            float vq = lp[cc] * wsf[WS_TVAL + cc];
            unsigned short h = f2bf(vq);
            ph[jc] = h;
            pl[jc] = f2bf(vq - bf2f(h));
          }
        }
      }
      int phys = (t * 4 + (g ^ ((t >> 1) & 3))) * 8;
      *(u16x8*)(qh + phys) = ph;
      *(u16x8*)(ql + phys) = pl;
    }
  }
  __syncthreads();

  // Gram via MFMA (K=96: hi.hi + lo.hi + hi.lo), elementwise-dot with kernel values
  float part = 0.f;
  #pragma unroll
  for (int ch = 0; ch < 3; ++ch) {
    const short* qa = (ch == 1) ? tA[1] : tA[0];
    const short* qb = (ch == 2) ? tB[1] : tB[0];
    bf16x8 af[4], bfr[4];
    #pragma unroll
    for (int mt = 0; mt < 4; mt++)
      af[mt] = frag32(qa, woff_m + mt * 16 + fr, fg);
    #pragma unroll
    for (int nt = 0; nt < 4; nt++)
      bfr[nt] = frag32(qb, woff_n + nt * 16 + fr, fg);
    #pragma unroll
    for (int mt = 0; mt < 4; mt++)
      #pragma unroll
      for (int nt = 0; nt < 4; nt++) {
        f32x4 z = (f32x4){0.f, 0.f, 0.f, 0.f};
        f32x4 g = __builtin_amdgcn_mfma_f32_16x16x32_bf16(af[mt], bfr[nt], z, 0, 0, 0);
        part += acc[mt][nt].x * g.x + acc[mt][nt].y * g.y
              + acc[mt][nt].z * g.z + acc[mt][nt].w * g.w;
      }
  }
  part *= mult;
  #pragma unroll
  for (int off = 32; off; off >>= 1) part += __shfl_down(part, off);
  if (lane == 0) red[w] = part;
  __syncthreads();

  // wave-0 finalize: bucketed atomic + release counter; last block sums & writes out
  if (w == 0) {
    float bs = red[0] + red[1] + red[2] + red[3];
    if (lane == 0) atomicAdd(&wsf[WS_ACCB + (blockIdx.x & 63) * 16], bs);
    int old = 0;
    if (lane == 0)
      old = __hip_atomic_fetch_add((int*)&wsf[WS_CNT], 1,
                                   __ATOMIC_RELEASE, __HIP_MEMORY_SCOPE_AGENT);
    old = __shfl(old, 0);
    if (old == NBLK - 1) {
      __builtin_amdgcn_fence(__ATOMIC_ACQUIRE, "agent");
      float t = __hip_atomic_load(&wsf[WS_ACCB + lane * 16],
                                  __ATOMIC_RELAXED, __HIP_MEMORY_SCOPE_AGENT);
      #pragma unroll
      for (int off = 32; off; off >>= 1) t += __shfl_down(t, off);
      if (lane == 0) out[0] = t * wsf[WS_SL];
    }
  }
}

extern "C" void kernel_launch(void* const* d_in, const int* in_sizes, int n_in,
                              void* d_out, int out_size, void* d_ws, size_t ws_size,
                              hipStream_t stream) {
  const float* src    = (const float*)d_in[0];
  const float* tgt    = (const float*)d_in[1];
  const int*   label  = (const int*)d_in[2];
  const float* logits = (const float*)d_in[3];
  const int*   iter_p = (const int*)d_in[4];
  float* wsf = (float*)d_ws;
  unsigned short* Xc = (unsigned short*)((char*)d_ws + WS_XC_BYTES);
  float* out = (float*)d_out;

  hipMemsetAsync(d_ws, 0, 24576, stream);   // zero counters/flag/buckets/stats
  k_all<<<NBLK, 256, 0, stream>>>(src, tgt, label, logits, iter_p, wsf, Xc, out);
}

// Round 9
// 199.322 us; speedup vs baseline: 1.4385x; 1.4385x over previous
//
#include <hip/hip_runtime.h>
#include <math.h>

#define NCLS 31
#define B 4096
#define D 512
#define N 8192
#define BT 128
#define NT (N / BT)               // 64 tiles per dim
#define NBLK (NT * (NT + 1) / 2)  // 2080 upper-tri tiles
#define BK32 32                   // bf16 K-chunk per iteration (triple-buffered)
#define NITER 16                  // K=512: pure-bf16 X dot (error ~5e-7 << 1.2e-4 thr)
#define NPRE 1024                 // k_pre blocks (8 rows each)

// ws float-index layout (memset zeroes first 24576 B = 6144 floats)
#define WS_SUMSQB 0      // 8 bucketed sumsq accumulators
#define WS_NBT    9
#define WS_SL     10
#define WS_CNT    11     // int done-counter (k_main)
#define WS_CNT2   12     // int done-counter (k_pre)
#define WS_HIST   16     // 31 ints
#define WS_PRES   47     // unsigned mask
#define WS_CSUM   48     // 31 floats
#define WS_SVAL   80     // 32
#define WS_TVAL   112    // 32
#define WS_ACCB   256    // 64 buckets, stride 16 floats (one line each)
#define WS_COLP   1280   // 8*512 bucketed column-sum partials (ends 5376)
#define WS_SQ     5376   // 8192 row squared norms (fully written by k_pre)
#define WS_XC_BYTES 65536  // Xc: bf16 [8192][512] row-major, 8 MB

typedef __attribute__((ext_vector_type(8))) short bf16x8;
typedef __attribute__((ext_vector_type(4))) float f32x4;
typedef __attribute__((ext_vector_type(8))) unsigned short u16x8;
typedef __attribute__((ext_vector_type(2))) unsigned int u32x2;

__device__ __forceinline__ unsigned short f2bf(float x) {
  unsigned u = __float_as_uint(x);
  u += 0x7fffu + ((u >> 16) & 1u);  // RNE (inputs finite)
  return (unsigned short)(u >> 16);
}
__device__ __forceinline__ float bf2f(unsigned short b) {
  return __uint_as_float(((unsigned)b) << 16);
}
// pack 4 floats -> 4 bf16 in a u32x2 (for nontemporal 8 B store)
__device__ __forceinline__ u32x2 pack4(float x, float y, float z, float w) {
  u32x2 r;
  r[0] = (unsigned)f2bf(x) | ((unsigned)f2bf(y) << 16);
  r[1] = (unsigned)f2bf(z) | ((unsigned)f2bf(w) << 16);
  return r;
}

__device__ __forceinline__ void async_lds16(const unsigned short* g, const short* l) {
  __builtin_amdgcn_global_load_lds(
      (const __attribute__((address_space(1))) unsigned int*)g,
      (__attribute__((address_space(3))) unsigned int*)l, 16, 0, 0);
}

// BK=32 tile: rows of 64 B = 4 granules of 16 B; XOR swizzle on (r>>1)&3
__device__ __forceinline__ bf16x8 frag32(const short* buf, int r, int g) {
  int sg = g ^ ((r >> 1) & 3);
  return *(const bf16x8*)(buf + (r * 4 + sg) * 8);
}

// R9 k_pre: R4 lean body + NONTEMPORAL Xc stores. Theory: the invariant ~75 µs
// pre+boundary cost is the 8 MB of Xc dirty L2 lines — written back at the
// boundary and re-fetched by k_main (R6 showed the cost migrating when the
// flush moved). NT stores never dirty L2 -> write-combine to memory during
// k_pre -> boundary flush has ~nothing to do.
__global__ void k_pre(const float* __restrict__ src, const float* __restrict__ tgt,
                      const int* __restrict__ label, const float* __restrict__ logits,
                      const int* __restrict__ iter_p, float* __restrict__ wsf,
                      unsigned short* __restrict__ Xc) {
  __shared__ __align__(16) float colbuf[4][512];
  __shared__ int lcnt[32];
  __shared__ float lcsum[32];
  __shared__ unsigned lpres;
  __shared__ float red_[4];
  __shared__ int lastblk;
  const int tid = threadIdx.x, w = tid >> 6, lane = tid & 63;
  const int b = blockIdx.x;
  if (tid < 32) { lcnt[tid] = 0; lcsum[tid] = 0.f; }
  if (tid == 0) lpres = 0u;
  // (no barrier: lcnt/lcsum/lpres are produced & consumed by wave 0 only)

  float4 ca = {0.f, 0.f, 0.f, 0.f}, cb = {0.f, 0.f, 0.f, 0.f};
  float wssq = 0.f;
  #pragma unroll
  for (int r = 0; r < 2; ++r) {            // 2 rows per wave, 8 rows per block
    const int row = b * 8 + r * 4 + w;
    const float* p = (row < B) ? src + (size_t)row * D : tgt + (size_t)(row - B) * D;
    float4 a  = ((const float4*)p)[lane];        // cols lane*4 .. +4
    float4 bb = ((const float4*)p)[lane + 64];   // cols 256+lane*4 .. +4
    size_t rb8 = (size_t)row * 512;
    __builtin_nontemporal_store(pack4(a.x, a.y, a.z, a.w),
                                (u32x2*)(Xc + rb8 + lane * 4));
    __builtin_nontemporal_store(pack4(bb.x, bb.y, bb.z, bb.w),
                                (u32x2*)(Xc + rb8 + 256 + lane * 4));
    float s = a.x*a.x + a.y*a.y + a.z*a.z + a.w*a.w
            + bb.x*bb.x + bb.y*bb.y + bb.z*bb.z + bb.w*bb.w;
    ca.x += a.x;  ca.y += a.y;  ca.z += a.z;  ca.w += a.w;
    cb.x += bb.x; cb.y += bb.y; cb.z += bb.z; cb.w += bb.w;
    #pragma unroll
    for (int off = 32; off; off >>= 1) s += __shfl_down(s, off);
    if (lane == 0) { wsf[WS_SQ + row] = s; wssq += s; }
  }

  // class stats for this block's 8 rows (wave 0 only; same-wave ordering)
  {
    const int r0 = b * 8;
    if (r0 < B) {
      if (tid < 8) atomicAdd(&lcnt[label[r0 + tid]], 1);
      if (tid < NCLS && lcnt[tid]) atomicAdd((int*)&wsf[WS_HIST] + tid, lcnt[tid]);
    } else {
      if (tid < 8) {
        const float* lp = logits + (size_t)(r0 - B + tid) * NCLS;
        float mx = -1e30f; int am = 0;
        #pragma unroll
        for (int c = 0; c < NCLS; c++) {
          float v = lp[c];
          atomicAdd(&lcsum[c], v);
          if (v > mx) { mx = v; am = c; }  // strict >: first max, matches argmax
        }
        atomicOr(&lpres, 1u << am);
      }
      if (tid < NCLS) atomicAdd(&wsf[WS_CSUM + tid], lcsum[tid]);
      if (tid == 0) atomicOr((unsigned*)&wsf[WS_PRES], lpres);
    }
  }

  // cross-wave column reduce (one barrier) + block sumsq via red_
  *(float4*)&colbuf[w][lane * 4]       = ca;   // dense float4: conflict-free
  *(float4*)&colbuf[w][256 + lane * 4] = cb;
  if (lane == 0) red_[w] = wssq;
  __syncthreads();
  {
    float c0 = colbuf[0][tid] + colbuf[1][tid] + colbuf[2][tid] + colbuf[3][tid];
    float c1 = colbuf[0][tid+256] + colbuf[1][tid+256] + colbuf[2][tid+256] + colbuf[3][tid+256];
    const int bkt = (b & 7) * 512;
    atomicAdd(&wsf[WS_COLP + bkt + tid], c0);
    atomicAdd(&wsf[WS_COLP + bkt + 256 + tid], c1);
    if (tid == 0)
      atomicAdd(&wsf[WS_SUMSQB + (b & 7)], red_[0] + red_[1] + red_[2] + red_[3]);
  }

  // done-counter; last block finalizes stats
  __syncthreads();
  if (tid == 0)
    lastblk = (__hip_atomic_fetch_add((int*)&wsf[WS_CNT2], 1,
               __ATOMIC_RELEASE, __HIP_MEMORY_SCOPE_AGENT) == NPRE - 1);
  __syncthreads();
  if (!lastblk) return;
  __threadfence();  // acquire: see all blocks' atomics/stores
  float cs0 = 0.f, cs1 = 0.f;
  #pragma unroll
  for (int bk = 0; bk < 8; bk++) {
    cs0 += wsf[WS_COLP + bk * 512 + tid];
    cs1 += wsf[WS_COLP + bk * 512 + 256 + tid];
  }
  float v = cs0 * cs0 + cs1 * cs1;
  #pragma unroll
  for (int off = 32; off; off >>= 1) v += __shfl_down(v, off);
  if (lane == 0) red_[w] = v;
  __syncthreads();
  if (tid < 32) {
    // one class per lane (parallel loads), ballot for the mask count
    unsigned presT = *(unsigned*)&wsf[WS_PRES];
    const int c = tid;
    int cnt = (c < NCLS) ? ((int*)&wsf[WS_HIST])[c] : 0;
    float csum = (c < NCLS) ? wsf[WS_CSUM + c] : 0.f;
    bool m = (cnt > 0) && ((presT >> c) & 1u);
    if (csum == 0.f) csum = 100.f;
    wsf[WS_SVAL + c] = m ? 1.f / (float)cnt : 0.f;
    wsf[WS_TVAL + c] = m ? -1.f / csum : 0.f;
    unsigned long long bal = __ballot(m);
    if (tid == 0) {
      int cm = __popcll(bal);
      float scale = (cm > 0) ? 1.f / (float)cm : 0.f;
      float pp = (float)iter_p[0] / 1000.f;
      float lamb = 2.f / (1.f + __expf(-pp)) - 1.f;
      wsf[WS_SL] = scale * lamb;
      double colnorm2 = (double)red_[0] + red_[1] + red_[2] + red_[3];
      double sumsq = 0.0;
      for (int bk = 0; bk < 8; bk++) sumsq += (double)wsf[WS_SUMSQB + bk];
      double sumL2 = 2.0 * (double)N * sumsq - 2.0 * colnorm2;
      wsf[WS_NBT] = (float)(-((double)N * (double)N - (double)N) / (4.0 * sumL2));
    }
  }
}

// k_main: R4 body (validated 96 µs, VGPR 84, no spills) + T1 XCD-chunk swizzle
// on the tile index (2080 % 8 == 0 -> bijective): consecutive tri-tiles share
// the i-panel; chunking puts them on the same XCD's L2 instead of striping
// across all 8 (the measured 82 MB FETCH ~ 8 XCDs x full Xc).
__launch_bounds__(256, 3)
__global__ void k_main(const unsigned short* __restrict__ Xc,
                       const int* __restrict__ label, const float* __restrict__ logits,
                       float* __restrict__ wsf, float* __restrict__ out) {
  __shared__ __align__(16) short tA[3][BT * BK32];   // 3 x 8 KB
  __shared__ __align__(16) short tB[3][BT * BK32];   // 3 x 8 KB
  __shared__ float sqi[BT], sqj[BT];
  __shared__ float red[4];

  // T1 swizzle: XCD (bid&7) gets a contiguous chunk of 260 tri-tiles
  int bid = ((int)blockIdx.x & 7) * (NBLK / 8) + ((int)blockIdx.x >> 3);
  // triangular block decode: bi <= bj, S(bi) = bi*(129-bi)/2
  int bi = (int)(64.5f - sqrtf(64.5f * 64.5f - 2.0f * (float)bid));
  while (bi > 0 && bid < (bi * (129 - bi)) / 2) --bi;
  while (bid >= ((bi + 1) * (128 - bi)) / 2) ++bi;
  int bj = bi + (bid - (bi * (129 - bi)) / 2);
  const int i0 = bi * BT, j0 = bj * BT;
  const float mult = (bi == bj) ? 1.f : 2.f;

  const int tid = threadIdx.x;
  const int w = tid >> 6, lane = tid & 63;
  const int woff_m = (w >> 1) * 64, woff_n = (w & 1) * 64;
  const int fr = lane & 15, fg = lane >> 4;       // fragment row / k-group
  // staging: each inst covers 16 rows x 64 B; lane -> (r_local, swizzled granule)
  const int s_r  = lane >> 2;                     // r_local 0..15
  const int s_g  = (lane & 3) ^ ((s_r >> 1) & 3); // logical granule (inverts swizzle)

  // issue staging for iteration `it` (K-offset it*32) into buffer `bf`
  #define ISSUE(it, bf) do {                                                   \
    const int off = (it) * 32;                                                 \
    _Pragma("unroll")                                                          \
    for (int q = 0; q < 2; ++q) {                                              \
      const int inst = w * 2 + q;              /* 0..7, 16 rows each */        \
      const int rl = inst * 16 + s_r;                                          \
      async_lds16(Xc + (size_t)(i0 + rl) * 512 + off + s_g * 8,                \
                  &tA[bf][inst * 512]);                                        \
      async_lds16(Xc + (size_t)(j0 + rl) * 512 + off + s_g * 8,                \
                  &tB[bf][inst * 512]);                                        \
    }                                                                          \
  } while (0)

  ISSUE(0, 0);
  ISSUE(1, 1);

  if (tid < 128) sqi[tid] = wsf[WS_SQ + i0 + tid];
  else           sqj[tid - 128] = wsf[WS_SQ + j0 + (tid - 128)];
  const float nbt = wsf[WS_NBT];

  f32x4 acc[4][4];
  #pragma unroll
  for (int mt = 0; mt < 4; mt++)
    #pragma unroll
    for (int nt = 0; nt < 4; nt++) acc[mt][nt] = (f32x4){0.f, 0.f, 0.f, 0.f};

  __syncthreads();  // full drain: buf0/buf1 staged, sq/nbt loads retired (vmcnt=0)

  #pragma unroll
  for (int it = 0; it < NITER; ++it) {
    // outstanding at top of it: {ISSUE(it), ISSUE(it+1)} (8) for it>=2;
    // it in {0,1}: data already drained by the prologue __syncthreads.
    if (it >= 1) {
      if (it >= 2 && it < NITER - 1)
        asm volatile("s_waitcnt vmcnt(4)" ::: "memory");
      if (it == NITER - 1)
        asm volatile("s_waitcnt vmcnt(0)" ::: "memory");
      __builtin_amdgcn_s_barrier();
      __builtin_amdgcn_sched_barrier(0);
    }
    const int cur = it % 3;
    bf16x8 af[4], bfr[4];
    #pragma unroll
    for (int mt = 0; mt < 4; mt++)
      af[mt] = frag32(tA[cur], woff_m + mt * 16 + fr, fg);
    #pragma unroll
    for (int nt = 0; nt < 4; nt++)
      bfr[nt] = frag32(tB[cur], woff_n + nt * 16 + fr, fg);
    // overwrite the buffer consumed at it-1: (it+2)%3 == (it-1)%3; all waves'
    // reads of it retired before they crossed this iteration's barrier.
    if (it + 2 < NITER) ISSUE(it + 2, (it + 2) % 3);
    #pragma unroll
    for (int mt = 0; mt < 4; mt++)
      #pragma unroll
      for (int nt = 0; nt < 4; nt++)
        acc[mt][nt] = __builtin_amdgcn_mfma_f32_16x16x32_bf16(
            af[mt], bfr[nt], acc[mt][nt], 0, 0, 0);
  }
  #undef ISSUE

  // acc -> multi-band Gaussian kernel: t + t^2 + t^4 + t^8 + t^16
  float sj4[4], si16[4][4];
  #pragma unroll
  for (int nt = 0; nt < 4; nt++) sj4[nt] = sqj[woff_n + nt * 16 + fr];
  #pragma unroll
  for (int mt = 0; mt < 4; mt++)
    #pragma unroll
    for (int t = 0; t < 4; t++) si16[mt][t] = sqi[woff_m + mt * 16 + fg * 4 + t];
  #pragma unroll
  for (int mt = 0; mt < 4; mt++)
    #pragma unroll
    for (int nt = 0; nt < 4; nt++)
      #pragma unroll
      for (int t = 0; t < 4; t++) {
        float d2 = fmaxf(si16[mt][t] + sj4[nt] - 2.f * acc[mt][nt][t], 0.f);
        float e1 = __expf(d2 * nbt);
        float e2 = e1 * e1, e4 = e2 * e2, e8 = e4 * e4, e16 = e8 * e8;
        acc[mt][nt][t] = ((e16 + e8) + (e4 + e2)) + e1;
      }

  // build Q tiles: Qi-hi->tA[0], Qi-lo->tA[1], Qj-hi->tB[0], Qj-lo->tB[1]
  __syncthreads();
  {
    const int t = tid & 127;
    short* qh = (tid < 128) ? tA[0] : tB[0];
    short* ql = (tid < 128) ? tA[1] : tB[1];
    const int gq = ((tid < 128) ? i0 : j0) + t;
    const int lab = (gq < B) ? label[gq] : -1;
    const float sv = (gq < B) ? wsf[WS_SVAL + lab] : 0.f;
    const float* lp = (gq < B) ? (const float*)0 : logits + (size_t)(gq - B) * NCLS;
    #pragma unroll
    for (int g = 0; g < 4; ++g) {
      u16x8 ph = (u16x8){0,0,0,0,0,0,0,0}, pl = (u16x8){0,0,0,0,0,0,0,0};
      const int cbase = g * 8;
      if (gq < B) {
        if (lab >= cbase && lab < cbase + 8) {
          unsigned short h = f2bf(sv);
          ph[lab - cbase] = h;
          pl[lab - cbase] = f2bf(sv - bf2f(h));
        }
      } else {
        #pragma unroll
        for (int jc = 0; jc < 8; ++jc) {
          int cc = cbase + jc;
          if (cc < NCLS) {
            float vq = lp[cc] * wsf[WS_TVAL + cc];
            unsigned short h = f2bf(vq);
            ph[jc] = h;
            pl[jc] = f2bf(vq - bf2f(h));
          }
        }
      }
      int phys = (t * 4 + (g ^ ((t >> 1) & 3))) * 8;
      *(u16x8*)(qh + phys) = ph;
      *(u16x8*)(ql + phys) = pl;
    }
  }
  __syncthreads();

  // Gram via MFMA (K=96: hi.hi + lo.hi + hi.lo), elementwise-dot with kernel values
  float part = 0.f;
  #pragma unroll
  for (int ch = 0; ch < 3; ++ch) {
    const short* qa = (ch == 1) ? tA[1] : tA[0];
    const short* qb = (ch == 2) ? tB[1] : tB[0];
    bf16x8 af[4], bfr[4];
    #pragma unroll
    for (int mt = 0; mt < 4; mt++)
      af[mt] = frag32(qa, woff_m + mt * 16 + fr, fg);
    #pragma unroll
    for (int nt = 0; nt < 4; nt++)
      bfr[nt] = frag32(qb, woff_n + nt * 16 + fr, fg);
    #pragma unroll
    for (int mt = 0; mt < 4; mt++)
      #pragma unroll
      for (int nt = 0; nt < 4; nt++) {
        f32x4 z = (f32x4){0.f, 0.f, 0.f, 0.f};
        f32x4 g = __builtin_amdgcn_mfma_f32_16x16x32_bf16(af[mt], bfr[nt], z, 0, 0, 0);
        part += acc[mt][nt].x * g.x + acc[mt][nt].y * g.y
              + acc[mt][nt].z * g.z + acc[mt][nt].w * g.w;
      }
  }
  part *= mult;
  #pragma unroll
  for (int off = 32; off; off >>= 1) part += __shfl_down(part, off);
  if (lane == 0) red[w] = part;
  __syncthreads();

  // wave-0 finalize: bucketed atomic + release counter; last block sums & writes out
  if (w == 0) {
    float bs = red[0] + red[1] + red[2] + red[3];
    if (lane == 0) atomicAdd(&wsf[WS_ACCB + (blockIdx.x & 63) * 16], bs);
    int old = 0;
    if (lane == 0)
      old = __hip_atomic_fetch_add((int*)&wsf[WS_CNT], 1,
                                   __ATOMIC_RELEASE, __HIP_MEMORY_SCOPE_AGENT);
    old = __shfl(old, 0);
    if (old == NBLK - 1) {
      __builtin_amdgcn_fence(__ATOMIC_ACQUIRE, "agent");
      float t = __hip_atomic_load(&wsf[WS_ACCB + lane * 16],
                                  __ATOMIC_RELAXED, __HIP_MEMORY_SCOPE_AGENT);
      #pragma unroll
      for (int off = 32; off; off >>= 1) t += __shfl_down(t, off);
      if (lane == 0) out[0] = t * wsf[WS_SL];
    }
  }
}

extern "C" void kernel_launch(void* const* d_in, const int* in_sizes, int n_in,
                              void* d_out, int out_size, void* d_ws, size_t ws_size,
                              hipStream_t stream) {
  const float* src    = (const float*)d_in[0];
  const float* tgt    = (const float*)d_in[1];
  const int*   label  = (const int*)d_in[2];
  const float* logits = (const float*)d_in[3];
  const int*   iter_p = (const int*)d_in[4];
  float* wsf = (float*)d_ws;
  unsigned short* Xc = (unsigned short*)((char*)d_ws + WS_XC_BYTES);
  float* out = (float*)d_out;

  hipMemsetAsync(d_ws, 0, 24576, stream);   // zero scalars/counters/buckets/stats
  k_pre<<<NPRE, 256, 0, stream>>>(src, tgt, label, logits, iter_p, wsf, Xc);
  k_main<<<NBLK, 256, 0, stream>>>(Xc, label, logits, wsf, out);
}